// Round 9
// baseline (146.014 us; speedup 1.0000x reference)
//
#include <hip/hip_runtime.h>
#include <hip/hip_bf16.h>

typedef __hip_bfloat16 bf16;
typedef __bf16 bfx8 __attribute__((ext_vector_type(8)));
typedef float f32x4 __attribute__((ext_vector_type(4)));

#define Bk   8
#define Ck   384
#define NHk  8
#define Dk   48
#define Dp   64
#define Nk   1024
#define O3   1152

// ---------------------------------------------------------------------------
// ALL MFMA operands live in fragment-order swizzle [R/16][C/8][16][8]: a
// wave's fragment load = base + lane*16B = one contiguous 1KB burst (R8).
//
// Workspace (bf16 elems):
//   Xs: [b][n/16][48][16][8]        3,145,728   (x^T swizzled)
//   Wq: [o/16][48][16][8]             442,368
//   Wp: [o/16][48][16][8]             147,456
//   Qs: [b][hd][n/16][8][16][8]     4,194,304   (scale*log2e folded; chunks 6,7 zero)
//   Ks: [b][hd][n/16][8][16][8]     4,194,304   (chunks 6,7 zero)
//   Vs: [b][hd][d/16][n/8][16][8]   3,145,728   (V^T swizzled)
//   AO: [b][n/16][48][16][8]        3,145,728   (swizzled for proj)
// ---------------------------------------------------------------------------

// Prep 1: transpose+convert x [b][c][n] fp32 -> Xs swizzled bf16.
__global__ __launch_bounds__(256) void xpose_kernel(
    const float* __restrict__ x, bf16* __restrict__ Xs)
{
    __shared__ bf16 tile[32][33];
    const int b = blockIdx.z, c0 = blockIdx.y * 32, n0 = blockIdx.x * 32;
    const int tn = threadIdx.x & 31, tc = threadIdx.x >> 5;
    const float* xb = x + (size_t)b * Ck * Nk;
    #pragma unroll
    for (int i = 0; i < 4; ++i)
        tile[tc + 8 * i][tn] = __float2bfloat16(xb[(size_t)(c0 + tc + 8 * i) * Nk + n0 + tn]);
    __syncthreads();
    bf16* base = Xs + ((size_t)b * 64 + (n0 >> 4)) * 48 * 128 + (c0 >> 3) * 128;
    #pragma unroll
    for (int i = 0; i < 4; ++i) {
        int n_loc = tc + 8 * i, c_loc = tn;
        base[(size_t)(n_loc >> 4) * 6144 + (c_loc >> 3) * 128 +
             (n_loc & 15) * 8 + (c_loc & 7)] = tile[c_loc][n_loc];
    }
}

// Prep 2: convert+swizzle weights; ALSO zero Q/K pad chunks (cd=6,7).
__global__ __launch_bounds__(256) void wconv_kernel(
    const float* __restrict__ wq, const float* __restrict__ wp,
    bf16* __restrict__ Wq, bf16* __restrict__ Wp,
    bf16* __restrict__ Qs, bf16* __restrict__ Ks)
{
    int i = blockIdx.x * 256 + threadIdx.x;
    if (i < O3 * Ck) {
        int o = i / Ck, c = i - o * Ck;
        Wq[((size_t)(o >> 4) * 48 + (c >> 3)) * 128 + (o & 15) * 8 + (c & 7)] =
            __float2bfloat16(wq[i]);
    }
    if (i < Ck * Ck) {
        int o = i / Ck, c = i - o * Ck;
        Wp[((size_t)(o >> 4) * 48 + (c >> 3)) * 128 + (o & 15) * 8 + (c & 7)] =
            __float2bfloat16(wp[i]);
    }
    if (i < 262144) {           // 2 bufs x 64 heads x 64 grp x 2 chunks x 16 int4
        int buf = i >> 17;
        int r17 = i & 131071;
        int head = r17 >> 11;
        int r11 = r17 & 2047;
        int g = r11 >> 5, c5 = r11 & 31;
        int cd = 6 + (c5 >> 4), e = c5 & 15;
        bf16* p = (buf ? Ks : Qs) + (size_t)head * 65536 +
                  ((size_t)g * 8 + cd) * 128 + e * 8;
        *(int4*)p = (int4){0, 0, 0, 0};
    }
}

// ---------------------------------------------------------------------------
// Kernel 1: QKV GEMM, pure-MFMA, no LDS; epilogue scatters into the
// fragment-order Qs/Ks/Vs layouts.
// ---------------------------------------------------------------------------
__global__ __launch_bounds__(256) void qkv_mfma_kernel(
    const bf16* __restrict__ Xs, const bf16* __restrict__ Wq,
    const float* __restrict__ bias,
    bf16* __restrict__ Qs, bf16* __restrict__ Ks, bf16* __restrict__ Vs)
{
    const int b    = blockIdx.z;
    const int by   = blockIdx.y;
    const int bx   = blockIdx.x;
    const int o0   = by * 64;
    const int n0   = bx * 128;
    const int wave = threadIdx.x >> 6;
    const int lane = threadIdx.x & 63;
    const int l15  = lane & 15, quad = lane >> 4;
    const int t3   = o0 / Ck;

    const bf16* xg[2];
    const bf16* wg[4];
    #pragma unroll
    for (int i = 0; i < 2; ++i)
        xg[i] = Xs + ((size_t)(b * 64 + bx * 8 + wave * 2 + i) * 48) * 128 + lane * 8;
    #pragma unroll
    for (int j = 0; j < 4; ++j)
        wg[j] = Wq + ((size_t)(by * 4 + j) * 48) * 128 + lane * 8;

    f32x4 acc[8];
    #pragma unroll
    for (int i = 0; i < 8; ++i) acc[i] = (f32x4){0.f, 0.f, 0.f, 0.f};

    if (t3 < 2) {
        #pragma unroll
        for (int s = 0; s < 12; ++s) {
            bfx8 fx[2], fw[4];
            #pragma unroll
            for (int i = 0; i < 2; ++i) fx[i] = *(const bfx8*)(xg[i] + s * 512);
            #pragma unroll
            for (int j = 0; j < 4; ++j) fw[j] = *(const bfx8*)(wg[j] + s * 512);
            #pragma unroll
            for (int i = 0; i < 2; ++i)
                #pragma unroll
                for (int j = 0; j < 4; ++j)
                    acc[i * 4 + j] = __builtin_amdgcn_mfma_f32_16x16x32_bf16(
                        fx[i], fw[j], acc[i * 4 + j], 0, 0, 0);
        }
        // 48^-0.5 * log2(e) folded into Q (softmax uses exp2)
        const float qscale = 0.2082350964f;
        #pragma unroll
        for (int j = 0; j < 4; ++j) {
            int o  = o0 + j * 16 + l15;
            float bi = bias[o];
            int r  = o - t3 * Ck;
            int hd = r / Dk, d = r - hd * Dk;
            bf16* hb = (t3 == 0 ? Qs : Ks) + (size_t)(b * NHk + hd) * 65536
                     + (d >> 3) * 128 + (d & 7);
            #pragma unroll
            for (int i = 0; i < 2; ++i) {
                #pragma unroll
                for (int reg = 0; reg < 4; ++reg) {
                    int npos = n0 + wave * 32 + i * 16 + quad * 4 + reg;
                    float v = acc[i * 4 + j][reg] + bi;
                    if (t3 == 0) v *= qscale;
                    hb[(size_t)(npos >> 4) * 1024 + (npos & 15) * 8] = __float2bfloat16(v);
                }
            }
        }
    } else {
        #pragma unroll
        for (int s = 0; s < 12; ++s) {
            bfx8 fx[2], fw[4];
            #pragma unroll
            for (int i = 0; i < 2; ++i) fx[i] = *(const bfx8*)(xg[i] + s * 512);
            #pragma unroll
            for (int j = 0; j < 4; ++j) fw[j] = *(const bfx8*)(wg[j] + s * 512);
            #pragma unroll
            for (int j = 0; j < 4; ++j)
                #pragma unroll
                for (int i = 0; i < 2; ++i)
                    acc[j * 2 + i] = __builtin_amdgcn_mfma_f32_16x16x32_bf16(
                        fw[j], fx[i], acc[j * 2 + i], 0, 0, 0);
        }
        #pragma unroll
        for (int j = 0; j < 4; ++j) {
            #pragma unroll
            for (int reg = 0; reg < 4; ++reg) {
                int o  = o0 + j * 16 + quad * 4 + reg;
                float bi = bias[o];
                int r  = o - 2 * Ck;
                int hd = r / Dk, d = r - hd * Dk;
                bf16* vb = Vs + (size_t)(b * NHk + hd) * 49152
                         + ((size_t)(d >> 4) * 128) * 128 + (d & 15) * 8;
                #pragma unroll
                for (int i = 0; i < 2; ++i) {
                    int npos = n0 + wave * 32 + i * 16 + l15;
                    vb[(size_t)(npos >> 3) * 128 + (npos & 7)] =
                        __float2bfloat16(acc[j * 2 + i][reg] + bi);
                }
            }
        }
    }
}

// ---------------------------------------------------------------------------
// Kernel 2: MFMA attention — NO LDS staging, NO barriers. All Q/K/V fragments
// are direct 1KB global bursts from swizzled layouts; only the per-wave P
// round-trip uses LDS. Softmax: no-max exp2 (scale*log2e folded into Q).
// ---------------------------------------------------------------------------
__global__ __launch_bounds__(256) void attn_kernel(
    const bf16* __restrict__ Qs, const bf16* __restrict__ Ks,
    const bf16* __restrict__ Vs, bf16* __restrict__ AO)
{
    __shared__ __align__(16) short Ps[4 * 32 * 72];
    __shared__ float sums[4][32];

    const int bx   = blockIdx.x;
    const int hd   = blockIdx.y;
    const int b    = blockIdx.z;
    const int t    = threadIdx.x;
    const int wave = t >> 6;
    const int lane = t & 63;
    const int l15  = lane & 15;
    const int quad = lane >> 4;

    const bf16* qb = Qs + (size_t)(b * NHk + hd) * 65536;
    const bf16* kb = Ks + (size_t)(b * NHk + hd) * 65536;
    const bf16* vb = Vs + (size_t)(b * NHk + hd) * 49152;

    // Q fragments (burst loads)
    bfx8 bq[2][2];
    #pragma unroll
    for (int g = 0; g < 2; ++g) {
        const bf16* qp = qb + ((size_t)(bx * 8 + wave * 2 + g) * 8 + quad) * 128 + l15 * 8;
        bq[g][0] = *(const bfx8*)(qp);
        bq[g][1] = *(const bfx8*)(qp + 512);
    }

    float l_run[2] = {0.f, 0.f};
    f32x4 oacc[2][3];
    #pragma unroll
    for (int g = 0; g < 2; ++g)
        #pragma unroll
        for (int dc = 0; dc < 3; ++dc) oacc[g][dc] = (f32x4){0.f, 0.f, 0.f, 0.f};

    short* PsW = Ps + wave * 32 * 72;

    for (int k0 = 0; k0 < Nk; k0 += 64) {
        // S^T = K Q^T: D[key][q]; K fragments streamed straight from L2
        f32x4 sf[4][2];
        #pragma unroll
        for (int s = 0; s < 4; ++s) {
            const bf16* kp = kb + ((size_t)((k0 >> 4) + s) * 8 + quad) * 128 + l15 * 8;
            const bfx8 kf0 = *(const bfx8*)(kp);
            const bfx8 kf1 = *(const bfx8*)(kp + 512);
            #pragma unroll
            for (int g = 0; g < 2; ++g) {
                f32x4 z = (f32x4){0.f, 0.f, 0.f, 0.f};
                z = __builtin_amdgcn_mfma_f32_16x16x32_bf16(kf0, bq[g][0], z, 0, 0, 0);
                z = __builtin_amdgcn_mfma_f32_16x16x32_bf16(kf1, bq[g][1], z, 0, 0, 0);
                sf[s][g] = z;
            }
        }

        // exp2 (no max subtraction), pack 4 keys -> b64 write, accumulate l
        #pragma unroll
        for (int g = 0; g < 2; ++g) {
            float lsum = 0.f;
            #pragma unroll
            for (int s = 0; s < 4; ++s) {
                ushort4 pk;
                float e0 = __builtin_amdgcn_exp2f(sf[s][g][0]);
                float e1 = __builtin_amdgcn_exp2f(sf[s][g][1]);
                float e2 = __builtin_amdgcn_exp2f(sf[s][g][2]);
                float e3 = __builtin_amdgcn_exp2f(sf[s][g][3]);
                lsum += (e0 + e1) + (e2 + e3);
                bf16 h0 = __float2bfloat16(e0), h1 = __float2bfloat16(e1);
                bf16 h2 = __float2bfloat16(e2), h3 = __float2bfloat16(e3);
                pk.x = *(unsigned short*)&h0; pk.y = *(unsigned short*)&h1;
                pk.z = *(unsigned short*)&h2; pk.w = *(unsigned short*)&h3;
                *(ushort4*)&PsW[(g * 16 + l15) * 72 + s * 16 + quad * 4] = pk;
            }
            l_run[g] += lsum;
        }

        asm volatile("s_waitcnt lgkmcnt(0)" ::: "memory");

        // O += P V: A-frag from per-wave LDS, V fragments from L2 bursts
        bfx8 ap[2][2];
        #pragma unroll
        for (int g = 0; g < 2; ++g) {
            ap[g][0] = *(const bfx8*)&PsW[(g * 16 + l15) * 72 + quad * 8];
            ap[g][1] = *(const bfx8*)&PsW[(g * 16 + l15) * 72 + 32 + quad * 8];
        }
        #pragma unroll
        for (int dc = 0; dc < 3; ++dc) {
            const bf16* vp = vb + ((size_t)dc * 128 + (k0 >> 3) + quad) * 128 + l15 * 8;
            const bfx8 bv0 = *(const bfx8*)(vp);
            const bfx8 bv1 = *(const bfx8*)(vp + 512);
            #pragma unroll
            for (int g = 0; g < 2; ++g) {
                oacc[g][dc] = __builtin_amdgcn_mfma_f32_16x16x32_bf16(ap[g][0], bv0, oacc[g][dc], 0, 0, 0);
                oacc[g][dc] = __builtin_amdgcn_mfma_f32_16x16x32_bf16(ap[g][1], bv1, oacc[g][dc], 0, 0, 0);
            }
        }
    }

    #pragma unroll
    for (int g = 0; g < 2; ++g) {
        float lt = l_run[g];
        lt += __shfl_xor(lt, 16, 64);
        lt += __shfl_xor(lt, 32, 64);
        sums[wave][g * 16 + l15] = lt;
    }
    asm volatile("s_waitcnt lgkmcnt(0)" ::: "memory");

    short* OsW = PsW;
    #pragma unroll
    for (int g = 0; g < 2; ++g) {
        #pragma unroll
        for (int r = 0; r < 4; ++r) {
            int qi = g * 16 + quad * 4 + r;
            float rli = 1.0f / sums[wave][qi];
            #pragma unroll
            for (int dcc = 0; dcc < 3; ++dcc) {
                bf16 hb = __float2bfloat16(oacc[g][dcc][r] * rli);
                OsW[qi * 64 + dcc * 16 + l15] = *(short*)&hb;
            }
        }
    }
    asm volatile("s_waitcnt lgkmcnt(0)" ::: "memory");

    #pragma unroll
    for (int g = 0; g < 2; ++g) {
        bf16* aob = AO + (((size_t)b * 64 + bx * 8 + wave * 2 + g) * 48 + hd * 6) * 128;
        int u = lane;
        int4 v = *(const int4*)&OsW[(g * 16 + (u & 15)) * 64 + (u >> 4) * 8];
        *(int4*)(aob + u * 8) = v;
        if (lane < 32) {
            int u2 = 64 + lane;
            int4 v2 = *(const int4*)&OsW[(g * 16 + (u2 & 15)) * 64 + (u2 >> 4) * 8];
            *(int4*)(aob + u2 * 8) = v2;
        }
    }
}

// ---------------------------------------------------------------------------
// Kernel 3: projection GEMM, pure-MFMA, swizzled operands (unchanged R8).
// ---------------------------------------------------------------------------
__global__ __launch_bounds__(256) void proj_mfma_kernel(
    const bf16* __restrict__ AO, const bf16* __restrict__ Wp,
    const float* __restrict__ bias, float* __restrict__ out)
{
    const int b    = blockIdx.z;
    const int by   = blockIdx.y;
    const int bx   = blockIdx.x;
    const int o0   = by * 64;
    const int n0   = bx * 128;
    const int wave = threadIdx.x >> 6;
    const int lane = threadIdx.x & 63;
    const int l15  = lane & 15, quad = lane >> 4;

    const bf16* ag[2];
    const bf16* wg[4];
    #pragma unroll
    for (int i = 0; i < 2; ++i)
        ag[i] = AO + ((size_t)(b * 64 + bx * 8 + wave * 2 + i) * 48) * 128 + lane * 8;
    #pragma unroll
    for (int j = 0; j < 4; ++j)
        wg[j] = Wp + ((size_t)(by * 4 + j) * 48) * 128 + lane * 8;

    f32x4 acc[8];
    #pragma unroll
    for (int i = 0; i < 8; ++i) acc[i] = (f32x4){0.f, 0.f, 0.f, 0.f};

    #pragma unroll
    for (int s = 0; s < 12; ++s) {
        bfx8 fx[2], fw[4];
        #pragma unroll
        for (int i = 0; i < 2; ++i) fx[i] = *(const bfx8*)(ag[i] + s * 512);
        #pragma unroll
        for (int j = 0; j < 4; ++j) fw[j] = *(const bfx8*)(wg[j] + s * 512);
        #pragma unroll
        for (int j = 0; j < 4; ++j)
            #pragma unroll
            for (int i = 0; i < 2; ++i)
                acc[j * 2 + i] = __builtin_amdgcn_mfma_f32_16x16x32_bf16(
                    fw[j], fx[i], acc[j * 2 + i], 0, 0, 0);
    }

    #pragma unroll
    for (int j = 0; j < 4; ++j) {
        #pragma unroll
        for (int reg = 0; reg < 4; ++reg) {
            int o  = o0 + j * 16 + quad * 4 + reg;
            float bi = bias[o];
            #pragma unroll
            for (int i = 0; i < 2; ++i) {
                int npos = n0 + wave * 32 + i * 16 + l15;
                out[((size_t)b * Ck + o) * Nk + npos] = acc[j * 2 + i][reg] + bi;
            }
        }
    }
}

extern "C" void kernel_launch(void* const* d_in, const int* in_sizes, int n_in,
                              void* d_out, int out_size, void* d_ws, size_t ws_size,
                              hipStream_t stream)
{
    const float* x      = (const float*)d_in[0];
    const float* w_qkv  = (const float*)d_in[1];
    const float* b_qkv  = (const float*)d_in[2];
    const float* w_proj = (const float*)d_in[3];
    const float* b_proj = (const float*)d_in[4];
    float* out = (float*)d_out;

    const size_t XT_SEG = (size_t)Bk * Nk * Ck;
    const size_t WQ_SEG = (size_t)O3 * Ck;
    const size_t WP_SEG = (size_t)Ck * Ck;
    const size_t QK_SEG = (size_t)Bk * NHk * Nk * Dp;
    const size_t V_SEG  = (size_t)Bk * NHk * Dk * Nk;

    bf16* Xs = (bf16*)d_ws;
    bf16* Wq = Xs + XT_SEG;
    bf16* Wp = Wq + WQ_SEG;
    bf16* Qs = Wp + WP_SEG;
    bf16* Ks = Qs + QK_SEG;
    bf16* Vs = Ks + QK_SEG;
    bf16* AO = Vs + V_SEG;

    xpose_kernel<<<dim3(Nk / 32, Ck / 32, Bk), 256, 0, stream>>>(x, Xs);
    wconv_kernel<<<(O3 * Ck + 255) / 256, 256, 0, stream>>>(
        w_qkv, w_proj, Wq, Wp, Qs, Ks);
    qkv_mfma_kernel<<<dim3(Nk / 128, O3 / 64, Bk), 256, 0, stream>>>(
        Xs, Wq, b_qkv, Qs, Ks, Vs);
    attn_kernel<<<dim3(Nk / 128, NHk, Bk), 256, 0, stream>>>(Qs, Ks, Vs, AO);
    proj_mfma_kernel<<<dim3(Nk / 128, Ck / 64, Bk), 256, 0, stream>>>(
        AO, Wp, b_proj, out);
}

// Round 10
// 134.323 us; speedup vs baseline: 1.0870x; 1.0870x over previous
//
#include <hip/hip_runtime.h>
#include <hip/hip_bf16.h>

typedef __hip_bfloat16 bf16;
typedef __bf16 bfx8 __attribute__((ext_vector_type(8)));
typedef float f32x4 __attribute__((ext_vector_type(4)));

#define Bk   8
#define Ck   384
#define NHk  8
#define Dk   48
#define Dp   64
#define Nk   1024
#define O3   1152

// ---------------------------------------------------------------------------
// ALL MFMA operands live in fragment-order swizzle [R/16][C/8][16][8]: a
// wave's fragment load = base + lane*16B = one contiguous 1KB burst (R8).
//
// Workspace (bf16 elems):
//   Xs: [b][n/16][48][16][8]        3,145,728   (x^T swizzled)
//   Wq: [o/16][48][16][8]             442,368
//   Wp: [o/16][48][16][8]             147,456
//   Qs: [b][hd][n/16][8][16][8]     4,194,304   (scale*log2e folded; chunks 6,7 zero)
//   Ks: [b][hd][n/16][8][16][8]     4,194,304   (chunks 6,7 zero)
//   Vs: [b][hd][d/16][n/8][16][8]   3,145,728   (V^T swizzled)
//   AO: [b][n/16][48][16][8]        3,145,728   (swizzled for proj)
// ---------------------------------------------------------------------------

// Prep 1: transpose+convert x [b][c][n] fp32 -> Xs swizzled bf16.
__global__ __launch_bounds__(256) void xpose_kernel(
    const float* __restrict__ x, bf16* __restrict__ Xs)
{
    __shared__ bf16 tile[32][33];
    const int b = blockIdx.z, c0 = blockIdx.y * 32, n0 = blockIdx.x * 32;
    const int tn = threadIdx.x & 31, tc = threadIdx.x >> 5;
    const float* xb = x + (size_t)b * Ck * Nk;
    #pragma unroll
    for (int i = 0; i < 4; ++i)
        tile[tc + 8 * i][tn] = __float2bfloat16(xb[(size_t)(c0 + tc + 8 * i) * Nk + n0 + tn]);
    __syncthreads();
    bf16* base = Xs + ((size_t)b * 64 + (n0 >> 4)) * 48 * 128 + (c0 >> 3) * 128;
    #pragma unroll
    for (int i = 0; i < 4; ++i) {
        int n_loc = tc + 8 * i, c_loc = tn;
        base[(size_t)(n_loc >> 4) * 6144 + (c_loc >> 3) * 128 +
             (n_loc & 15) * 8 + (c_loc & 7)] = tile[c_loc][n_loc];
    }
}

// Prep 2: convert+swizzle weights; ALSO zero Q/K pad chunks (cd=6,7).
__global__ __launch_bounds__(256) void wconv_kernel(
    const float* __restrict__ wq, const float* __restrict__ wp,
    bf16* __restrict__ Wq, bf16* __restrict__ Wp,
    bf16* __restrict__ Qs, bf16* __restrict__ Ks)
{
    int i = blockIdx.x * 256 + threadIdx.x;
    if (i < O3 * Ck) {
        int o = i / Ck, c = i - o * Ck;
        Wq[((size_t)(o >> 4) * 48 + (c >> 3)) * 128 + (o & 15) * 8 + (c & 7)] =
            __float2bfloat16(wq[i]);
    }
    if (i < Ck * Ck) {
        int o = i / Ck, c = i - o * Ck;
        Wp[((size_t)(o >> 4) * 48 + (c >> 3)) * 128 + (o & 15) * 8 + (c & 7)] =
            __float2bfloat16(wp[i]);
    }
    if (i < 262144) {           // 2 bufs x 64 heads x 64 grp x 2 chunks x 16 int4
        int buf = i >> 17;
        int r17 = i & 131071;
        int head = r17 >> 11;
        int r11 = r17 & 2047;
        int g = r11 >> 5, c5 = r11 & 31;
        int cd = 6 + (c5 >> 4), e = c5 & 15;
        bf16* p = (buf ? Ks : Qs) + (size_t)head * 65536 +
                  ((size_t)g * 8 + cd) * 128 + e * 8;
        *(int4*)p = (int4){0, 0, 0, 0};
    }
}

// ---------------------------------------------------------------------------
// Kernel 1: QKV GEMM, pure-MFMA, no LDS (unchanged from R9).
// ---------------------------------------------------------------------------
__global__ __launch_bounds__(256) void qkv_mfma_kernel(
    const bf16* __restrict__ Xs, const bf16* __restrict__ Wq,
    const float* __restrict__ bias,
    bf16* __restrict__ Qs, bf16* __restrict__ Ks, bf16* __restrict__ Vs)
{
    const int b    = blockIdx.z;
    const int by   = blockIdx.y;
    const int bx   = blockIdx.x;
    const int o0   = by * 64;
    const int n0   = bx * 128;
    const int wave = threadIdx.x >> 6;
    const int lane = threadIdx.x & 63;
    const int l15  = lane & 15, quad = lane >> 4;
    const int t3   = o0 / Ck;

    const bf16* xg[2];
    const bf16* wg[4];
    #pragma unroll
    for (int i = 0; i < 2; ++i)
        xg[i] = Xs + ((size_t)(b * 64 + bx * 8 + wave * 2 + i) * 48) * 128 + lane * 8;
    #pragma unroll
    for (int j = 0; j < 4; ++j)
        wg[j] = Wq + ((size_t)(by * 4 + j) * 48) * 128 + lane * 8;

    f32x4 acc[8];
    #pragma unroll
    for (int i = 0; i < 8; ++i) acc[i] = (f32x4){0.f, 0.f, 0.f, 0.f};

    if (t3 < 2) {
        #pragma unroll
        for (int s = 0; s < 12; ++s) {
            bfx8 fx[2], fw[4];
            #pragma unroll
            for (int i = 0; i < 2; ++i) fx[i] = *(const bfx8*)(xg[i] + s * 512);
            #pragma unroll
            for (int j = 0; j < 4; ++j) fw[j] = *(const bfx8*)(wg[j] + s * 512);
            #pragma unroll
            for (int i = 0; i < 2; ++i)
                #pragma unroll
                for (int j = 0; j < 4; ++j)
                    acc[i * 4 + j] = __builtin_amdgcn_mfma_f32_16x16x32_bf16(
                        fx[i], fw[j], acc[i * 4 + j], 0, 0, 0);
        }
        // 48^-0.5 * log2(e) folded into Q (softmax uses exp2)
        const float qscale = 0.2082350964f;
        #pragma unroll
        for (int j = 0; j < 4; ++j) {
            int o  = o0 + j * 16 + l15;
            float bi = bias[o];
            int r  = o - t3 * Ck;
            int hd = r / Dk, d = r - hd * Dk;
            bf16* hb = (t3 == 0 ? Qs : Ks) + (size_t)(b * NHk + hd) * 65536
                     + (d >> 3) * 128 + (d & 7);
            #pragma unroll
            for (int i = 0; i < 2; ++i) {
                #pragma unroll
                for (int reg = 0; reg < 4; ++reg) {
                    int npos = n0 + wave * 32 + i * 16 + quad * 4 + reg;
                    float v = acc[i * 4 + j][reg] + bi;
                    if (t3 == 0) v *= qscale;
                    hb[(size_t)(npos >> 4) * 1024 + (npos & 15) * 8] = __float2bfloat16(v);
                }
            }
        }
    } else {
        #pragma unroll
        for (int s = 0; s < 12; ++s) {
            bfx8 fx[2], fw[4];
            #pragma unroll
            for (int i = 0; i < 2; ++i) fx[i] = *(const bfx8*)(xg[i] + s * 512);
            #pragma unroll
            for (int j = 0; j < 4; ++j) fw[j] = *(const bfx8*)(wg[j] + s * 512);
            #pragma unroll
            for (int j = 0; j < 4; ++j)
                #pragma unroll
                for (int i = 0; i < 2; ++i)
                    acc[j * 2 + i] = __builtin_amdgcn_mfma_f32_16x16x32_bf16(
                        fw[j], fx[i], acc[j * 2 + i], 0, 0, 0);
        }
        #pragma unroll
        for (int j = 0; j < 4; ++j) {
            #pragma unroll
            for (int reg = 0; reg < 4; ++reg) {
                int o  = o0 + j * 16 + quad * 4 + reg;
                float bi = bias[o];
                int r  = o - 2 * Ck;
                int hd = r / Dk, d = r - hd * Dk;
                bf16* vb = Vs + (size_t)(b * NHk + hd) * 49152
                         + ((size_t)(d >> 4) * 128) * 128 + (d & 15) * 8;
                #pragma unroll
                for (int i = 0; i < 2; ++i) {
                    int npos = n0 + wave * 32 + i * 16 + l15;
                    vb[(size_t)(npos >> 3) * 128 + (npos & 7)] =
                        __float2bfloat16(acc[j * 2 + i][reg] + bi);
                }
            }
        }
    }
}

// ---------------------------------------------------------------------------
// Kernel 2: MFMA attention — 64 q per block (16 q per wave), grid 1024 blocks
// = 4 blocks/CU = 16 waves/CU (R9 post-mortem: latency x concurrency bound at
// 2 blocks/CU; this doubles TLP). No barriers; Q/K/V fragments are direct
// 1KB swizzled global bursts; only the per-wave P round-trip uses LDS.
// ---------------------------------------------------------------------------
__global__ __launch_bounds__(256) void attn_kernel(
    const bf16* __restrict__ Qs, const bf16* __restrict__ Ks,
    const bf16* __restrict__ Vs, bf16* __restrict__ AO)
{
    __shared__ __align__(16) short Ps[4 * 16 * 72];
    __shared__ float sums[4][16];

    const int bx   = blockIdx.x;        // 16 q-tiles of 64
    const int hd   = blockIdx.y;
    const int b    = blockIdx.z;
    const int t    = threadIdx.x;
    const int wave = t >> 6;
    const int lane = t & 63;
    const int l15  = lane & 15;
    const int quad = lane >> 4;
    const int grp  = bx * 4 + wave;     // q group (16 q) 0..63

    const bf16* qb = Qs + (size_t)(b * NHk + hd) * 65536;
    const bf16* kb = Ks + (size_t)(b * NHk + hd) * 65536;
    const bf16* vb = Vs + (size_t)(b * NHk + hd) * 49152;

    // Q fragments (burst loads): B[k=d][n=q=l15]
    const bf16* qp = qb + ((size_t)grp * 8 + quad) * 128 + l15 * 8;
    const bfx8 bq0 = *(const bfx8*)(qp);
    const bfx8 bq1 = *(const bfx8*)(qp + 512);

    float l_run = 0.f;
    f32x4 oacc[3];
    #pragma unroll
    for (int dc = 0; dc < 3; ++dc) oacc[dc] = (f32x4){0.f, 0.f, 0.f, 0.f};

    short* PsW = Ps + wave * 16 * 72;

    for (int k0 = 0; k0 < Nk; k0 += 64) {
        // S^T = K Q^T: D[key][q]; K fragments streamed from L2
        f32x4 sf[4];
        #pragma unroll
        for (int s = 0; s < 4; ++s) {
            const bf16* kp = kb + ((size_t)((k0 >> 4) + s) * 8 + quad) * 128 + l15 * 8;
            const bfx8 kf0 = *(const bfx8*)(kp);
            const bfx8 kf1 = *(const bfx8*)(kp + 512);
            f32x4 z = (f32x4){0.f, 0.f, 0.f, 0.f};
            z = __builtin_amdgcn_mfma_f32_16x16x32_bf16(kf0, bq0, z, 0, 0, 0);
            z = __builtin_amdgcn_mfma_f32_16x16x32_bf16(kf1, bq1, z, 0, 0, 0);
            sf[s] = z;
        }

        // exp2 (no max subtraction), pack 4 keys -> b64 write, accumulate l
        float lsum = 0.f;
        #pragma unroll
        for (int s = 0; s < 4; ++s) {
            ushort4 pk;
            float e0 = __builtin_amdgcn_exp2f(sf[s][0]);
            float e1 = __builtin_amdgcn_exp2f(sf[s][1]);
            float e2 = __builtin_amdgcn_exp2f(sf[s][2]);
            float e3 = __builtin_amdgcn_exp2f(sf[s][3]);
            lsum += (e0 + e1) + (e2 + e3);
            bf16 h0 = __float2bfloat16(e0), h1 = __float2bfloat16(e1);
            bf16 h2 = __float2bfloat16(e2), h3 = __float2bfloat16(e3);
            pk.x = *(unsigned short*)&h0; pk.y = *(unsigned short*)&h1;
            pk.z = *(unsigned short*)&h2; pk.w = *(unsigned short*)&h3;
            *(ushort4*)&PsW[l15 * 72 + s * 16 + quad * 4] = pk;
        }
        l_run += lsum;

        asm volatile("s_waitcnt lgkmcnt(0)" ::: "memory");

        // O += P V: A-frag from per-wave LDS, V fragments from L2 bursts
        const bfx8 ap0 = *(const bfx8*)&PsW[l15 * 72 + quad * 8];
        const bfx8 ap1 = *(const bfx8*)&PsW[l15 * 72 + 32 + quad * 8];
        #pragma unroll
        for (int dc = 0; dc < 3; ++dc) {
            const bf16* vp = vb + ((size_t)dc * 128 + (k0 >> 3) + quad) * 128 + l15 * 8;
            const bfx8 bv0 = *(const bfx8*)(vp);
            const bfx8 bv1 = *(const bfx8*)(vp + 512);
            oacc[dc] = __builtin_amdgcn_mfma_f32_16x16x32_bf16(ap0, bv0, oacc[dc], 0, 0, 0);
            oacc[dc] = __builtin_amdgcn_mfma_f32_16x16x32_bf16(ap1, bv1, oacc[dc], 0, 0, 0);
        }
    }

    // cross-lane reduce l over quads
    {
        float lt = l_run;
        lt += __shfl_xor(lt, 16, 64);
        lt += __shfl_xor(lt, 32, 64);
        sums[wave][l15] = lt;
    }
    asm volatile("s_waitcnt lgkmcnt(0)" ::: "memory");

    // normalize into per-wave LDS (stride 64 shorts, 16B-aligned rows)
    short* OsW = PsW;   // 16*64 = 1024 shorts < 1152 region
    #pragma unroll
    for (int r = 0; r < 4; ++r) {
        int qi = quad * 4 + r;
        float rli = 1.0f / sums[wave][qi];
        #pragma unroll
        for (int dcc = 0; dcc < 3; ++dcc) {
            bf16 hb = __float2bfloat16(oacc[dcc][r] * rli);
            OsW[qi * 64 + dcc * 16 + l15] = *(short*)&hb;
        }
    }
    asm volatile("s_waitcnt lgkmcnt(0)" ::: "memory");

    // swizzled AO store: group grp, chunks hd*6 + (0..5); 96 int4 units
    bf16* aob = AO + (((size_t)b * 64 + grp) * 48 + hd * 6) * 128;
    {
        int u = lane;
        int4 v = *(const int4*)&OsW[(u & 15) * 64 + (u >> 4) * 8];
        *(int4*)(aob + u * 8) = v;
        if (lane < 32) {
            int u2 = 64 + lane;
            int4 v2 = *(const int4*)&OsW[(u2 & 15) * 64 + (u2 >> 4) * 8];
            *(int4*)(aob + u2 * 8) = v2;
        }
    }
}

// ---------------------------------------------------------------------------
// Kernel 3: projection GEMM, pure-MFMA, swizzled operands (unchanged R8).
// ---------------------------------------------------------------------------
__global__ __launch_bounds__(256) void proj_mfma_kernel(
    const bf16* __restrict__ AO, const bf16* __restrict__ Wp,
    const float* __restrict__ bias, float* __restrict__ out)
{
    const int b    = blockIdx.z;
    const int by   = blockIdx.y;
    const int bx   = blockIdx.x;
    const int o0   = by * 64;
    const int n0   = bx * 128;
    const int wave = threadIdx.x >> 6;
    const int lane = threadIdx.x & 63;
    const int l15  = lane & 15, quad = lane >> 4;

    const bf16* ag[2];
    const bf16* wg[4];
    #pragma unroll
    for (int i = 0; i < 2; ++i)
        ag[i] = AO + ((size_t)(b * 64 + bx * 8 + wave * 2 + i) * 48) * 128 + lane * 8;
    #pragma unroll
    for (int j = 0; j < 4; ++j)
        wg[j] = Wp + ((size_t)(by * 4 + j) * 48) * 128 + lane * 8;

    f32x4 acc[8];
    #pragma unroll
    for (int i = 0; i < 8; ++i) acc[i] = (f32x4){0.f, 0.f, 0.f, 0.f};

    #pragma unroll
    for (int s = 0; s < 12; ++s) {
        bfx8 fx[2], fw[4];
        #pragma unroll
        for (int i = 0; i < 2; ++i) fx[i] = *(const bfx8*)(ag[i] + s * 512);
        #pragma unroll
        for (int j = 0; j < 4; ++j) fw[j] = *(const bfx8*)(wg[j] + s * 512);
        #pragma unroll
        for (int j = 0; j < 4; ++j)
            #pragma unroll
            for (int i = 0; i < 2; ++i)
                acc[j * 2 + i] = __builtin_amdgcn_mfma_f32_16x16x32_bf16(
                    fw[j], fx[i], acc[j * 2 + i], 0, 0, 0);
    }

    #pragma unroll
    for (int j = 0; j < 4; ++j) {
        #pragma unroll
        for (int reg = 0; reg < 4; ++reg) {
            int o  = o0 + j * 16 + quad * 4 + reg;
            float bi = bias[o];
            #pragma unroll
            for (int i = 0; i < 2; ++i) {
                int npos = n0 + wave * 32 + i * 16 + l15;
                out[((size_t)b * Ck + o) * Nk + npos] = acc[j * 2 + i][reg] + bi;
            }
        }
    }
}

extern "C" void kernel_launch(void* const* d_in, const int* in_sizes, int n_in,
                              void* d_out, int out_size, void* d_ws, size_t ws_size,
                              hipStream_t stream)
{
    const float* x      = (const float*)d_in[0];
    const float* w_qkv  = (const float*)d_in[1];
    const float* b_qkv  = (const float*)d_in[2];
    const float* w_proj = (const float*)d_in[3];
    const float* b_proj = (const float*)d_in[4];
    float* out = (float*)d_out;

    const size_t XT_SEG = (size_t)Bk * Nk * Ck;
    const size_t WQ_SEG = (size_t)O3 * Ck;
    const size_t WP_SEG = (size_t)Ck * Ck;
    const size_t QK_SEG = (size_t)Bk * NHk * Nk * Dp;
    const size_t V_SEG  = (size_t)Bk * NHk * Dk * Nk;

    bf16* Xs = (bf16*)d_ws;
    bf16* Wq = Xs + XT_SEG;
    bf16* Wp = Wq + WQ_SEG;
    bf16* Qs = Wp + WP_SEG;
    bf16* Ks = Qs + QK_SEG;
    bf16* Vs = Ks + QK_SEG;
    bf16* AO = Vs + V_SEG;

    xpose_kernel<<<dim3(Nk / 32, Ck / 32, Bk), 256, 0, stream>>>(x, Xs);
    wconv_kernel<<<(O3 * Ck + 255) / 256, 256, 0, stream>>>(
        w_qkv, w_proj, Wq, Wp, Qs, Ks);
    qkv_mfma_kernel<<<dim3(Nk / 128, O3 / 64, Bk), 256, 0, stream>>>(
        Xs, Wq, b_qkv, Qs, Ks, Vs);
    attn_kernel<<<dim3(16, NHk, Bk), 256, 0, stream>>>(Qs, Ks, Vs, AO);
    proj_mfma_kernel<<<dim3(Nk / 128, Ck / 64, Bk), 256, 0, stream>>>(
        AO, Wp, b_proj, out);
}